// Round 6
// baseline (138.804 us; speedup 1.0000x reference)
//
#include <hip/hip_runtime.h>
#include <hip/hip_bf16.h>

// Deformable conv via FUSED implicit GEMM on MFMA.
// B=8, C=256, H=W=64, O=256, K=3.
// Stages: prep ; xpose (x -> bf16 NHWC) ; offset_gemm ; dcn_fused.
// R6: dcn_fused BM 128->64, grid 256->512 (2 blocks/CU), LDS 86->50KB
//     (params packed: ly/lx f32x2 + corner pos u16 w/ validity bit).

#define HW 64
#define CCH 256
#define OCH 256
#define BB 8
#define KDIM 2304  // 9 * 256, order kk*256 + c

typedef __attribute__((ext_vector_type(8))) short bf16x8;
typedef __attribute__((ext_vector_type(8))) unsigned short u16x8;
typedef __attribute__((ext_vector_type(4))) float f32x4;
typedef __attribute__((ext_vector_type(2))) float f32x2;
typedef __attribute__((ext_vector_type(4))) unsigned short u16x4;
typedef __attribute__((ext_vector_type(4))) unsigned int u32x4;
typedef __attribute__((ext_vector_type(4))) int i32x4;

static __device__ inline unsigned short f2bf(float f) {
  unsigned u = __builtin_bit_cast(unsigned, f);
  u += 0x7FFFu + ((u >> 16) & 1u);  // RNE
  return (unsigned short)(u >> 16);
}
static __device__ inline float bf2f(unsigned short s) {
  return __builtin_bit_cast(float, (unsigned)s << 16);
}
static __device__ inline unsigned cvt_pk_bf16(float lo, float hi) {
  unsigned r;
  asm("v_cvt_pk_bf16_f32 %0, %1, %2" : "=v"(r) : "v"(lo), "v"(hi));
  return r;
}

#define GLL16(gsrc, ldst)                                                      \
  __builtin_amdgcn_global_load_lds(                                           \
      (const __attribute__((address_space(1))) void*)(gsrc),                  \
      (__attribute__((address_space(3))) void*)(ldst), 16, 0, 0)

// XCD-bijective swizzles (nwg % 8 == 0): XCD k gets a contiguous chunk.
static __device__ inline int xcd_swz256(int bid) {
  return (bid & 7) * 32 + (bid >> 3);
}
static __device__ inline int xcd_swz512(int bid) {
  return (bid & 7) * 64 + (bid >> 3);
}

// ---------------- prep ----------------
__global__ __launch_bounds__(256) void prep(const float* __restrict__ w_dcn,
                                            const float* __restrict__ w_off,
                                            unsigned short* __restrict__ W2,
                                            unsigned short* __restrict__ Wop,
                                            unsigned short* __restrict__ zp) {
  int i = blockIdx.x * 256 + threadIdx.x;
  if (i < 9 * 256 * 256) {
    int o = i / KDIM;
    int r = i - o * KDIM;
    int kk = r >> 8, c = r & 255;
    W2[i] = f2bf(w_dcn[((o << 8) + c) * 9 + kk]);
  }
  if (i < 32 * KDIM) {
    int n = i / KDIM;
    int r = i - n * KDIM;
    int kk = r >> 8, c = r & 255;
    Wop[i] = (n < 18) ? f2bf(w_off[((n << 8) + c) * 9 + kk]) : (unsigned short)0;
  }
  if (i < 512) zp[i] = 0;
}

// ---------------- xpose: NCHW f32 -> NHWC bf16 ----------------
__global__ __launch_bounds__(256) void xpose(const float* __restrict__ x,
                                             unsigned short* __restrict__ xTbf) {
  __shared__ float t[64][65];
  const int tid = threadIdx.x;
  const int bid = blockIdx.x;
  const int ct = bid & 3;
  const int pt = (bid >> 2) & 63;
  const int b = bid >> 8;
#pragma unroll
  for (int i = 0; i < 16; ++i) {
    int cl = i * 4 + (tid >> 6);
    int p = tid & 63;
    t[cl][p] = x[(((b << 8) + ct * 64 + cl) << 12) + pt * 64 + p];
  }
  __syncthreads();
#pragma unroll
  for (int i = 0; i < 4; ++i) {
    int pl = i * 16 + (tid >> 4);
    int c4 = (tid & 15) * 4;
    u16x4 v;
    v[0] = f2bf(t[c4][pl]);
    v[1] = f2bf(t[c4 + 1][pl]);
    v[2] = f2bf(t[c4 + 2][pl]);
    v[3] = f2bf(t[c4 + 3][pl]);
    *(u16x4*)(xTbf + (((size_t)((b << 12) + pt * 64 + pl)) << 8) + ct * 64 + c4) = v;
  }
}

// ---------------- offset_gemm (unchanged, validated) ----------------
__global__ __launch_bounds__(256) void offset_gemm(
    const unsigned short* __restrict__ xTbf, const unsigned short* __restrict__ Wop,
    const unsigned short* __restrict__ zp, const float* __restrict__ b_off,
    float* __restrict__ off_buf) {
  __shared__ short ldsA[2][128 * 32];
  __shared__ short ldsB[2][32 * 32];
  const int tid = threadIdx.x;
  const int lane = tid & 63;
  const int wid = __builtin_amdgcn_readfirstlane(tid >> 6);
  const int m0 = xcd_swz256(blockIdx.x) * 128;
  const int b = m0 >> 12;
  const unsigned short* xb = xTbf + ((size_t)b << 20);

  int hA[2], wA[2], scA[2];
#pragma unroll
  for (int g = 0; g < 2; ++g) {
    int r = wid * 32 + g * 16 + (lane >> 2);
    int pos = (m0 & 4095) + r;
    hA[g] = pos >> 6;
    wA[g] = pos & 63;
    scA[g] = ((lane & 3) ^ ((r >> 1) & 3)) * 8;
  }
  const int rB = wid * 16 + (lane >> 2);
  const unsigned short* srcB =
      Wop + (size_t)rB * KDIM + ((lane & 3) ^ ((rB >> 1) & 3)) * 8;

  const int l15 = lane & 15, l4 = lane >> 4;
  int offA[2], offB[2];
#pragma unroll
  for (int f = 0; f < 2; ++f) {
    int rA = wid * 32 + f * 16 + l15;
    offA[f] = rA * 32 + ((l4 ^ ((rA >> 1) & 3)) << 3);
    int rb = f * 16 + l15;
    offB[f] = rb * 32 + ((l4 ^ ((rb >> 1) & 3)) << 3);
  }

  const f32x4 z = {0.f, 0.f, 0.f, 0.f};
  f32x4 acc[2][2];
#pragma unroll
  for (int i = 0; i < 2; ++i)
#pragma unroll
    for (int j = 0; j < 2; ++j) acc[i][j] = z;

  auto stage = [&](int buf, int t) {
    const int kk = t >> 3;
    const int c0 = (t & 7) * 32;
    const int dy = kk / 3 - 1, dx = kk - (kk / 3) * 3 - 1;
#pragma unroll
    for (int g = 0; g < 2; ++g) {
      const int y = hA[g] + dy, xx = wA[g] + dx;
      const bool valid = ((unsigned)y < 64u) && ((unsigned)xx < 64u);
      const unsigned short* src =
          valid ? xb + ((((y << 6) + xx) << 8) + c0 + scA[g]) : zp + scA[g];
      GLL16(src, &ldsA[buf][((wid * 2 + g) * 64 + lane) * 8]);
    }
    if (wid < 2) GLL16(srcB + t * 32, &ldsB[buf][(wid * 64 + lane) * 8]);
  };

  stage(0, 0);
  __syncthreads();

  for (int t = 0; t < 72; ++t) {
    const int buf = t & 1;
    if (t < 71) stage(buf ^ 1, t + 1);
    bf16x8 af[2], bfr[2];
#pragma unroll
    for (int f = 0; f < 2; ++f) af[f] = *(const bf16x8*)&ldsA[buf][offA[f]];
#pragma unroll
    for (int f = 0; f < 2; ++f) bfr[f] = *(const bf16x8*)&ldsB[buf][offB[f]];
#pragma unroll
    for (int i = 0; i < 2; ++i)
#pragma unroll
      for (int j = 0; j < 2; ++j)
        acc[i][j] = __builtin_amdgcn_mfma_f32_16x16x32_bf16(af[i], bfr[j],
                                                            acc[i][j], 0, 0, 0);
    __syncthreads();
  }

#pragma unroll
  for (int j = 0; j < 2; ++j) {
    const int col = j * 16 + l15;
    if (col < 18) {
      const float bias = b_off[col];
#pragma unroll
      for (int i = 0; i < 2; ++i)
#pragma unroll
        for (int r = 0; r < 4; ++r) {
          const int m = m0 + wid * 32 + i * 16 + l4 * 4 + r;
          off_buf[(size_t)m * 18 + col] = acc[i][j][r] + bias;
        }
    }
  }
}

// ---------------- dcn_fused ----------------
// BM=64, BN=256, BK=32, 512 threads (8 waves: wm=wid&1 -> 32 rows,
// wn=wid>>1 -> 64 cols). grid=512 -> 2 blocks/CU.
// Sampling role: r=tid>>3 (row), q=tid&7 (4-channel chunk).
__global__ __launch_bounds__(512, 4) void dcn_fused(
    const unsigned short* __restrict__ xTbf, const float* __restrict__ off_buf,
    const unsigned short* __restrict__ W2, float* __restrict__ out) {
  __shared__ f32x2 slyx[64][9];    // (ly, lx)
  __shared__ u16x4 spos[64][9];    // corner pos (12b) | validity<<15
  __shared__ short ldsA[2][64 * 32];
  __shared__ short ldsB[2][256 * 32];

  const int tid = threadIdx.x;
  const int lane = tid & 63;
  const int wid = __builtin_amdgcn_readfirstlane(tid >> 6);
  const int m0 = xcd_swz512(blockIdx.x) * 64;
  const int b = m0 >> 12;
  const unsigned short* xb = xTbf + ((size_t)b << 20);

  // ---- phase 0: sampling params for 64 rows x 9 taps ----
  for (int idx = tid; idx < 64 * 9; idx += 512) {
    const int r = idx / 9, k = idx - (idx / 9) * 9;
    const int ky = k / 3, kx = k - ky * 3;
    const int pos = (m0 & 4095) + r;
    const int h = pos >> 6, w = pos & 63;
    const float offy = off_buf[(size_t)(m0 + r) * 18 + 2 * k];
    const float offx = off_buf[(size_t)(m0 + r) * 18 + 2 * k + 1];
    const float sy = offy + (float)(h - 1 + ky);
    const float sx = offx + (float)(w - 1 + kx);
    const float y0f = floorf(sy), x0f = floorf(sx);
    const int y0 = (int)y0f, x0 = (int)x0f;
    const int y1 = y0 + 1, x1 = x0 + 1;
    const unsigned vy0 = ((unsigned)y0 < 64u), vy1 = ((unsigned)y1 < 64u);
    const unsigned vx0 = ((unsigned)x0 < 64u), vx1 = ((unsigned)x1 < 64u);
    const int y0c = min(max(y0, 0), HW - 1), y1c = min(max(y1, 0), HW - 1);
    const int x0c = min(max(x0, 0), HW - 1), x1c = min(max(x1, 0), HW - 1);
    f32x2 lyx;
    lyx[0] = sy - y0f;
    lyx[1] = sx - x0f;
    u16x4 pp;
    pp[0] = (unsigned short)(((y0c << 6) + x0c) | ((vy0 & vx0) << 15));
    pp[1] = (unsigned short)(((y0c << 6) + x1c) | ((vy0 & vx1) << 15));
    pp[2] = (unsigned short)(((y1c << 6) + x0c) | ((vy1 & vx0) << 15));
    pp[3] = (unsigned short)(((y1c << 6) + x1c) | ((vy1 & vx1) << 15));
    slyx[r][k] = lyx;
    spos[r][k] = pp;
  }

  // ---- roles ----
  const int r = tid >> 3, q = tid & 7;  // sampling: row, 4-ch chunk
  // swizzled A slot (shorts): 16B chunk cc=q>>1, half=q&1
  const int dstA = (r * 4 + ((q >> 1) ^ ((r >> 1) & 3))) * 8 + (q & 1) * 4;
  const int rowB = tid >> 2;
  const int scB = (tid & 3) ^ ((rowB >> 1) & 3);
  const unsigned short* srcB0 = W2 + (size_t)rowB * KDIM + scB * 8;
  const int rowB1 = 128 + rowB;
  const int scB1 = (tid & 3) ^ ((rowB1 >> 1) & 3);
  const unsigned short* srcB1 = W2 + (size_t)rowB1 * KDIM + scB1 * 8;

  const int l15 = lane & 15, l4 = lane >> 4;
  const int wm = wid & 1, wn = wid >> 1;
  int offA[2], offB[4];
#pragma unroll
  for (int f = 0; f < 2; ++f) {
    int rA = wm * 32 + f * 16 + l15;
    offA[f] = rA * 32 + ((l4 ^ ((rA >> 1) & 3)) << 3);
  }
#pragma unroll
  for (int f = 0; f < 4; ++f) {
    int rB = wn * 64 + f * 16 + l15;
    offB[f] = rB * 32 + ((l4 ^ ((rB >> 1) & 3)) << 3);
  }

  const f32x4 z = {0.f, 0.f, 0.f, 0.f};
  f32x4 acc[2][4];
#pragma unroll
  for (int i = 0; i < 2; ++i)
#pragma unroll
    for (int j = 0; j < 4; ++j) acc[i][j] = z;

  __syncthreads();  // params visible

  // per-thread param regs for current prefetch kk
  f32x4 wv;
  i32x4 av;
  auto load_params = [&](int kk) {
    const f32x2 lyx = slyx[r][kk];
    const u16x4 pp = spos[r][kk];
    const float ly = lyx[0], lx = lyx[1];
#pragma unroll
    for (int e = 0; e < 4; ++e) av[e] = (int)(pp[e] & 0x0FFFu) << 8;
    wv[0] = (1.f - ly) * (1.f - lx) * (float)(pp[0] >> 15);
    wv[1] = (1.f - ly) * lx * (float)(pp[1] >> 15);
    wv[2] = ly * (1.f - lx) * (float)(pp[2] >> 15);
    wv[3] = ly * lx * (float)(pp[3] >> 15);
  };
  load_params(0);

  auto lerp_pack = [&](const u16x4& c00, const u16x4& c01, const u16x4& c10,
                       const u16x4& c11, const f32x4& wt) -> u16x4 {
    unsigned words[2];
#pragma unroll
    for (int j = 0; j < 2; ++j) {
      float f0 = wt[0] * bf2f(c00[2 * j]) + wt[1] * bf2f(c01[2 * j]) +
                 wt[2] * bf2f(c10[2 * j]) + wt[3] * bf2f(c11[2 * j]);
      float f1 = wt[0] * bf2f(c00[2 * j + 1]) + wt[1] * bf2f(c01[2 * j + 1]) +
                 wt[2] * bf2f(c10[2 * j + 1]) + wt[3] * bf2f(c11[2 * j + 1]);
      words[j] = cvt_pk_bf16(f0, f1);
    }
    u16x4 o;
    o[0] = (unsigned short)(words[0] & 0xFFFFu);
    o[1] = (unsigned short)(words[0] >> 16);
    o[2] = (unsigned short)(words[1] & 0xFFFFu);
    o[3] = (unsigned short)(words[1] >> 16);
    return o;
  };

  // ---- prologue: stage tile 0 ----
  {
    const int ch = q * 4;
    u16x4 c00 = *(const u16x4*)(xb + av[0] + ch);
    u16x4 c01 = *(const u16x4*)(xb + av[1] + ch);
    u16x4 c10 = *(const u16x4*)(xb + av[2] + ch);
    u16x4 c11 = *(const u16x4*)(xb + av[3] + ch);
    *(u16x4*)&ldsA[0][dstA] = lerp_pack(c00, c01, c10, c11, wv);
    GLL16(srcB0, &ldsB[0][tid * 8]);
    GLL16(srcB1, &ldsB[0][(512 + tid) * 8]);
  }
  __syncthreads();

  // ---- main loop ----
  for (int t = 0; t < 72; ++t) {
    const int buf = t & 1;
    u16x4 c00, c01, c10, c11;
    f32x4 wcur;
    if (t < 71) {
      const int tn = t + 1;
      if ((tn & 7) == 0) load_params(tn >> 3);
      const int ch = (tn & 7) * 32 + q * 4;
      c00 = *(const u16x4*)(xb + av[0] + ch);  // issue early (T14)
      c01 = *(const u16x4*)(xb + av[1] + ch);
      c10 = *(const u16x4*)(xb + av[2] + ch);
      c11 = *(const u16x4*)(xb + av[3] + ch);
      wcur = wv;
      GLL16(srcB0 + tn * 32, &ldsB[buf ^ 1][tid * 8]);
      GLL16(srcB1 + tn * 32, &ldsB[buf ^ 1][(512 + tid) * 8]);
    }

    bf16x8 af[2], bfr[4];
#pragma unroll
    for (int f = 0; f < 2; ++f) af[f] = *(const bf16x8*)&ldsA[buf][offA[f]];
#pragma unroll
    for (int f = 0; f < 4; ++f) bfr[f] = *(const bf16x8*)&ldsB[buf][offB[f]];
#pragma unroll
    for (int i = 0; i < 2; ++i)
#pragma unroll
      for (int j = 0; j < 4; ++j)
        acc[i][j] = __builtin_amdgcn_mfma_f32_16x16x32_bf16(af[i], bfr[j],
                                                            acc[i][j], 0, 0, 0);

    if (t < 71)  // lerp late: gather latency hidden under the MFMAs above
      *(u16x4*)&ldsA[buf ^ 1][dstA] = lerp_pack(c00, c01, c10, c11, wcur);
    __syncthreads();
  }

  // ---- epilogue ----
#pragma unroll
  for (int i = 0; i < 2; ++i) {
    const int m = m0 + wm * 32 + i * 16 + l4 * 4;
    const int bb = m >> 12;
    const int pos = m & 4095;
#pragma unroll
    for (int j = 0; j < 4; ++j) {
      const int o = wn * 64 + j * 16 + l15;
      *(f32x4*)(out + (((size_t)bb * OCH + o) << 12) + pos) = acc[i][j];
    }
  }
}

extern "C" void kernel_launch(void* const* d_in, const int* in_sizes, int n_in,
                              void* d_out, int out_size, void* d_ws,
                              size_t ws_size, hipStream_t stream) {
  const float* x = (const float*)d_in[0];
  const float* w_off = (const float*)d_in[1];
  const float* b_off = (const float*)d_in[2];
  const float* w_dcn = (const float*)d_in[3];
  float* out = (float*)d_out;

  char* ws = (char*)d_ws;
  float* off_buf = (float*)(ws);                            //  2,359,296 B
  unsigned short* Wop = (unsigned short*)(ws + 2359296);    //    147,456 B
  unsigned short* zp = (unsigned short*)(ws + 2506752);     //      1,024 B
  unsigned short* W2 = (unsigned short*)(ws + 2507776);     //  1,179,648 B
  unsigned short* xTbf = (unsigned short*)(ws + 3687424);   // 16,777,216 B
  // total 20,464,640 B

  prep<<<2304, 256, 0, stream>>>(w_dcn, w_off, W2, Wop, zp);
  xpose<<<2048, 256, 0, stream>>>(x, xTbf);
  offset_gemm<<<256, 256, 0, stream>>>(xTbf, Wop, zp, b_off, off_buf);
  dcn_fused<<<512, 512, 0, stream>>>(xTbf, off_buf, W2, out);
}

// Round 7
// 134.142 us; speedup vs baseline: 1.0347x; 1.0347x over previous
//
#include <hip/hip_runtime.h>
#include <hip/hip_bf16.h>

// Deformable conv via FUSED implicit GEMM on MFMA.
// B=8, C=256, H=W=64, O=256, K=3.
// Stages: prep ; xpose (x -> bf16 NHWC) ; offset_gemm ; dcn_fused.
// R7: dcn_fused gets a 2-deep gather pipeline with counted-vmcnt raw barriers
//     (T4): per step, barrier waits vmcnt(4) -> drains the 2 GLL B-loads
//     (issued first, FIFO retire) but keeps the 4 corner gathers for t+2 in
//     flight across the barrier. T5 setprio around the MFMA cluster.

#define HW 64
#define CCH 256
#define OCH 256
#define BB 8
#define KDIM 2304  // 9 * 256, order kk*256 + c

typedef __attribute__((ext_vector_type(8))) short bf16x8;
typedef __attribute__((ext_vector_type(8))) unsigned short u16x8;
typedef __attribute__((ext_vector_type(4))) float f32x4;
typedef __attribute__((ext_vector_type(2))) float f32x2;
typedef __attribute__((ext_vector_type(4))) unsigned short u16x4;
typedef __attribute__((ext_vector_type(4))) unsigned int u32x4;
typedef __attribute__((ext_vector_type(4))) int i32x4;

static __device__ inline unsigned short f2bf(float f) {
  unsigned u = __builtin_bit_cast(unsigned, f);
  u += 0x7FFFu + ((u >> 16) & 1u);  // RNE
  return (unsigned short)(u >> 16);
}
static __device__ inline float bf2f(unsigned short s) {
  return __builtin_bit_cast(float, (unsigned)s << 16);
}
static __device__ inline unsigned cvt_pk_bf16(float lo, float hi) {
  unsigned r;
  asm("v_cvt_pk_bf16_f32 %0, %1, %2" : "=v"(r) : "v"(lo), "v"(hi));
  return r;
}

#define GLL16(gsrc, ldst)                                                      \
  __builtin_amdgcn_global_load_lds(                                           \
      (const __attribute__((address_space(1))) void*)(gsrc),                  \
      (__attribute__((address_space(3))) void*)(ldst), 16, 0, 0)

// XCD-bijective swizzles (nwg % 8 == 0): XCD k gets a contiguous chunk.
static __device__ inline int xcd_swz256(int bid) {
  return (bid & 7) * 32 + (bid >> 3);
}
static __device__ inline int xcd_swz512(int bid) {
  return (bid & 7) * 64 + (bid >> 3);
}

// ---------------- prep ----------------
__global__ __launch_bounds__(256) void prep(const float* __restrict__ w_dcn,
                                            const float* __restrict__ w_off,
                                            unsigned short* __restrict__ W2,
                                            unsigned short* __restrict__ Wop,
                                            unsigned short* __restrict__ zp) {
  int i = blockIdx.x * 256 + threadIdx.x;
  if (i < 9 * 256 * 256) {
    int o = i / KDIM;
    int r = i - o * KDIM;
    int kk = r >> 8, c = r & 255;
    W2[i] = f2bf(w_dcn[((o << 8) + c) * 9 + kk]);
  }
  if (i < 32 * KDIM) {
    int n = i / KDIM;
    int r = i - n * KDIM;
    int kk = r >> 8, c = r & 255;
    Wop[i] = (n < 18) ? f2bf(w_off[((n << 8) + c) * 9 + kk]) : (unsigned short)0;
  }
  if (i < 512) zp[i] = 0;
}

// ---------------- xpose: NCHW f32 -> NHWC bf16 ----------------
__global__ __launch_bounds__(256) void xpose(const float* __restrict__ x,
                                             unsigned short* __restrict__ xTbf) {
  __shared__ float t[64][65];
  const int tid = threadIdx.x;
  const int bid = blockIdx.x;
  const int ct = bid & 3;
  const int pt = (bid >> 2) & 63;
  const int b = bid >> 8;
#pragma unroll
  for (int i = 0; i < 16; ++i) {
    int cl = i * 4 + (tid >> 6);
    int p = tid & 63;
    t[cl][p] = x[(((b << 8) + ct * 64 + cl) << 12) + pt * 64 + p];
  }
  __syncthreads();
#pragma unroll
  for (int i = 0; i < 4; ++i) {
    int pl = i * 16 + (tid >> 4);
    int c4 = (tid & 15) * 4;
    u16x4 v;
    v[0] = f2bf(t[c4][pl]);
    v[1] = f2bf(t[c4 + 1][pl]);
    v[2] = f2bf(t[c4 + 2][pl]);
    v[3] = f2bf(t[c4 + 3][pl]);
    *(u16x4*)(xTbf + (((size_t)((b << 12) + pt * 64 + pl)) << 8) + ct * 64 + c4) = v;
  }
}

// ---------------- offset_gemm (unchanged, validated) ----------------
__global__ __launch_bounds__(256) void offset_gemm(
    const unsigned short* __restrict__ xTbf, const unsigned short* __restrict__ Wop,
    const unsigned short* __restrict__ zp, const float* __restrict__ b_off,
    float* __restrict__ off_buf) {
  __shared__ short ldsA[2][128 * 32];
  __shared__ short ldsB[2][32 * 32];
  const int tid = threadIdx.x;
  const int lane = tid & 63;
  const int wid = __builtin_amdgcn_readfirstlane(tid >> 6);
  const int m0 = xcd_swz256(blockIdx.x) * 128;
  const int b = m0 >> 12;
  const unsigned short* xb = xTbf + ((size_t)b << 20);

  int hA[2], wA[2], scA[2];
#pragma unroll
  for (int g = 0; g < 2; ++g) {
    int r = wid * 32 + g * 16 + (lane >> 2);
    int pos = (m0 & 4095) + r;
    hA[g] = pos >> 6;
    wA[g] = pos & 63;
    scA[g] = ((lane & 3) ^ ((r >> 1) & 3)) * 8;
  }
  const int rB = wid * 16 + (lane >> 2);
  const unsigned short* srcB =
      Wop + (size_t)rB * KDIM + ((lane & 3) ^ ((rB >> 1) & 3)) * 8;

  const int l15 = lane & 15, l4 = lane >> 4;
  int offA[2], offB[2];
#pragma unroll
  for (int f = 0; f < 2; ++f) {
    int rA = wid * 32 + f * 16 + l15;
    offA[f] = rA * 32 + ((l4 ^ ((rA >> 1) & 3)) << 3);
    int rb = f * 16 + l15;
    offB[f] = rb * 32 + ((l4 ^ ((rb >> 1) & 3)) << 3);
  }

  const f32x4 z = {0.f, 0.f, 0.f, 0.f};
  f32x4 acc[2][2];
#pragma unroll
  for (int i = 0; i < 2; ++i)
#pragma unroll
    for (int j = 0; j < 2; ++j) acc[i][j] = z;

  auto stage = [&](int buf, int t) {
    const int kk = t >> 3;
    const int c0 = (t & 7) * 32;
    const int dy = kk / 3 - 1, dx = kk - (kk / 3) * 3 - 1;
#pragma unroll
    for (int g = 0; g < 2; ++g) {
      const int y = hA[g] + dy, xx = wA[g] + dx;
      const bool valid = ((unsigned)y < 64u) && ((unsigned)xx < 64u);
      const unsigned short* src =
          valid ? xb + ((((y << 6) + xx) << 8) + c0 + scA[g]) : zp + scA[g];
      GLL16(src, &ldsA[buf][((wid * 2 + g) * 64 + lane) * 8]);
    }
    if (wid < 2) GLL16(srcB + t * 32, &ldsB[buf][(wid * 64 + lane) * 8]);
  };

  stage(0, 0);
  __syncthreads();

  for (int t = 0; t < 72; ++t) {
    const int buf = t & 1;
    if (t < 71) stage(buf ^ 1, t + 1);
    bf16x8 af[2], bfr[2];
#pragma unroll
    for (int f = 0; f < 2; ++f) af[f] = *(const bf16x8*)&ldsA[buf][offA[f]];
#pragma unroll
    for (int f = 0; f < 2; ++f) bfr[f] = *(const bf16x8*)&ldsB[buf][offB[f]];
#pragma unroll
    for (int i = 0; i < 2; ++i)
#pragma unroll
      for (int j = 0; j < 2; ++j)
        acc[i][j] = __builtin_amdgcn_mfma_f32_16x16x32_bf16(af[i], bfr[j],
                                                            acc[i][j], 0, 0, 0);
    __syncthreads();
  }

#pragma unroll
  for (int j = 0; j < 2; ++j) {
    const int col = j * 16 + l15;
    if (col < 18) {
      const float bias = b_off[col];
#pragma unroll
      for (int i = 0; i < 2; ++i)
#pragma unroll
        for (int r = 0; r < 4; ++r) {
          const int m = m0 + wid * 32 + i * 16 + l4 * 4 + r;
          off_buf[(size_t)m * 18 + col] = acc[i][j][r] + bias;
        }
    }
  }
}

// ---------------- dcn_fused ----------------
// BM=64, BN=256, BK=32, 512 threads (8 waves: wm rows, wn cols), grid=512.
// 2-deep gather pipeline: gathers for tile t+2 issued at step t, lerped at
// step t+1, consumed at t+2. Barrier = s_waitcnt vmcnt(4) + s_barrier
// (drains 2 GLLs, keeps 4 gathers in flight).
__global__ __launch_bounds__(512, 4) void dcn_fused(
    const unsigned short* __restrict__ xTbf, const float* __restrict__ off_buf,
    const unsigned short* __restrict__ W2, float* __restrict__ out) {
  __shared__ f32x2 slyx[64][9];    // (ly, lx)
  __shared__ u16x4 spos[64][9];    // corner pos (12b) | validity<<15
  __shared__ short ldsA[2][64 * 32];
  __shared__ short ldsB[2][256 * 32];

  const int tid = threadIdx.x;
  const int lane = tid & 63;
  const int wid = __builtin_amdgcn_readfirstlane(tid >> 6);
  const int m0 = xcd_swz512(blockIdx.x) * 64;
  const int b = m0 >> 12;
  const unsigned short* xb = xTbf + ((size_t)b << 20);

  // ---- phase 0: sampling params for 64 rows x 9 taps ----
  for (int idx = tid; idx < 64 * 9; idx += 512) {
    const int r = idx / 9, k = idx - (idx / 9) * 9;
    const int ky = k / 3, kx = k - ky * 3;
    const int pos = (m0 & 4095) + r;
    const int h = pos >> 6, w = pos & 63;
    const float offy = off_buf[(size_t)(m0 + r) * 18 + 2 * k];
    const float offx = off_buf[(size_t)(m0 + r) * 18 + 2 * k + 1];
    const float sy = offy + (float)(h - 1 + ky);
    const float sx = offx + (float)(w - 1 + kx);
    const float y0f = floorf(sy), x0f = floorf(sx);
    const int y0 = (int)y0f, x0 = (int)x0f;
    const int y1 = y0 + 1, x1 = x0 + 1;
    const unsigned vy0 = ((unsigned)y0 < 64u), vy1 = ((unsigned)y1 < 64u);
    const unsigned vx0 = ((unsigned)x0 < 64u), vx1 = ((unsigned)x1 < 64u);
    const int y0c = min(max(y0, 0), HW - 1), y1c = min(max(y1, 0), HW - 1);
    const int x0c = min(max(x0, 0), HW - 1), x1c = min(max(x1, 0), HW - 1);
    f32x2 lyx;
    lyx[0] = sy - y0f;
    lyx[1] = sx - x0f;
    u16x4 pp;
    pp[0] = (unsigned short)(((y0c << 6) + x0c) | ((vy0 & vx0) << 15));
    pp[1] = (unsigned short)(((y0c << 6) + x1c) | ((vy0 & vx1) << 15));
    pp[2] = (unsigned short)(((y1c << 6) + x0c) | ((vy1 & vx0) << 15));
    pp[3] = (unsigned short)(((y1c << 6) + x1c) | ((vy1 & vx1) << 15));
    slyx[r][k] = lyx;
    spos[r][k] = pp;
  }

  // ---- roles ----
  const int r = tid >> 3, q = tid & 7;  // sampling: row, 4-ch chunk
  const int dstA = (r * 4 + ((q >> 1) ^ ((r >> 1) & 3))) * 8 + (q & 1) * 4;
  const int rowB = tid >> 2;
  const int scB = (tid & 3) ^ ((rowB >> 1) & 3);
  const unsigned short* srcB0 = W2 + (size_t)rowB * KDIM + scB * 8;
  const int rowB1 = 128 + rowB;
  const int scB1 = (tid & 3) ^ ((rowB1 >> 1) & 3);
  const unsigned short* srcB1 = W2 + (size_t)rowB1 * KDIM + scB1 * 8;

  const int l15 = lane & 15, l4 = lane >> 4;
  const int wm = wid & 1, wn = wid >> 1;
  int offA[2], offB[4];
#pragma unroll
  for (int f = 0; f < 2; ++f) {
    int rA = wm * 32 + f * 16 + l15;
    offA[f] = rA * 32 + ((l4 ^ ((rA >> 1) & 3)) << 3);
  }
#pragma unroll
  for (int f = 0; f < 4; ++f) {
    int rB = wn * 64 + f * 16 + l15;
    offB[f] = rB * 32 + ((l4 ^ ((rB >> 1) & 3)) << 3);
  }

  const f32x4 z = {0.f, 0.f, 0.f, 0.f};
  f32x4 acc[2][4];
#pragma unroll
  for (int i = 0; i < 2; ++i)
#pragma unroll
    for (int j = 0; j < 4; ++j) acc[i][j] = z;

  __syncthreads();  // params visible

  // per-kk params (av at gather time; wv carried alongside the gathers)
  f32x4 wv;
  i32x4 av;
  auto load_params = [&](int kk) {
    const f32x2 lyx = slyx[r][kk];
    const u16x4 pp = spos[r][kk];
    const float ly = lyx[0], lx = lyx[1];
#pragma unroll
    for (int e = 0; e < 4; ++e) av[e] = (int)(pp[e] & 0x0FFFu) << 8;
    wv[0] = (1.f - ly) * (1.f - lx) * (float)(pp[0] >> 15);
    wv[1] = (1.f - ly) * lx * (float)(pp[1] >> 15);
    wv[2] = ly * (1.f - lx) * (float)(pp[2] >> 15);
    wv[3] = ly * lx * (float)(pp[3] >> 15);
  };

  auto lerp_pack = [&](const u16x4& c00, const u16x4& c01, const u16x4& c10,
                       const u16x4& c11, const f32x4& wt) -> u16x4 {
    unsigned words[2];
#pragma unroll
    for (int j = 0; j < 2; ++j) {
      float f0 = wt[0] * bf2f(c00[2 * j]) + wt[1] * bf2f(c01[2 * j]) +
                 wt[2] * bf2f(c10[2 * j]) + wt[3] * bf2f(c11[2 * j]);
      float f1 = wt[0] * bf2f(c00[2 * j + 1]) + wt[1] * bf2f(c01[2 * j + 1]) +
                 wt[2] * bf2f(c10[2 * j + 1]) + wt[3] * bf2f(c11[2 * j + 1]);
      words[j] = cvt_pk_bf16(f0, f1);
    }
    u16x4 o;
    o[0] = (unsigned short)(words[0] & 0xFFFFu);
    o[1] = (unsigned short)(words[0] >> 16);
    o[2] = (unsigned short)(words[1] & 0xFFFFu);
    o[3] = (unsigned short)(words[1] >> 16);
    return o;
  };

  // gather register sets (2-deep pipeline)
  u16x4 g0c00, g0c01, g0c10, g0c11;
  u16x4 g1c00, g1c01, g1c10, g1c11;
  f32x4 g0wv, g1wv;

  // ---- prologue ----
  load_params(0);
  {  // tile 0: gather + lerp inline -> ldsA[0]
    const int ch = q * 4;
    u16x4 c00 = *(const u16x4*)(xb + av[0] + ch);
    u16x4 c01 = *(const u16x4*)(xb + av[1] + ch);
    u16x4 c10 = *(const u16x4*)(xb + av[2] + ch);
    u16x4 c11 = *(const u16x4*)(xb + av[3] + ch);
    *(u16x4*)&ldsA[0][dstA] = lerp_pack(c00, c01, c10, c11, wv);
  }
  GLL16(srcB0, &ldsB[0][tid * 8]);
  GLL16(srcB1, &ldsB[0][(512 + tid) * 8]);
  __builtin_amdgcn_sched_barrier(0);
  {  // issue gathers for tile 1 (kk=0)
    const int ch = 32 + q * 4;
    g1c00 = *(const u16x4*)(xb + av[0] + ch);
    g1c01 = *(const u16x4*)(xb + av[1] + ch);
    g1c10 = *(const u16x4*)(xb + av[2] + ch);
    g1c11 = *(const u16x4*)(xb + av[3] + ch);
    g1wv = wv;
  }
  __syncthreads();  // one-time full drain

// step body: CB=read buf, NB=write buf, GINx consumed (tile t+1),
// GOUTx produced (tile t+2). vmcnt(4): GLLs (issued first) drained,
// 4 GOUT gathers stay in flight across the barrier.
#define FUSED_STEP(CB, NB, IC00, IC01, IC10, IC11, IWV, OC00, OC01, OC10,      \
                   OC11, OWV)                                                  \
  {                                                                            \
    GLL16(srcB0 + (t + 1) * 32, &ldsB[NB][tid * 8]);                           \
    GLL16(srcB1 + (t + 1) * 32, &ldsB[NB][(512 + tid) * 8]);                   \
    __builtin_amdgcn_sched_barrier(0);                                         \
    if (((t + 2) & 7) == 0) load_params((t + 2) >> 3);                         \
    {                                                                          \
      const int ch = ((t + 2) & 7) * 32 + q * 4;                               \
      OC00 = *(const u16x4*)(xb + av[0] + ch);                                 \
      OC01 = *(const u16x4*)(xb + av[1] + ch);                                 \
      OC10 = *(const u16x4*)(xb + av[2] + ch);                                 \
      OC11 = *(const u16x4*)(xb + av[3] + ch);                                 \
      OWV = wv;                                                                \
    }                                                                          \
    bf16x8 af[2], bfr[4];                                                      \
    af[0] = *(const bf16x8*)&ldsA[CB][offA[0]];                                \
    af[1] = *(const bf16x8*)&ldsA[CB][offA[1]];                                \
    bfr[0] = *(const bf16x8*)&ldsB[CB][offB[0]];                               \
    bfr[1] = *(const bf16x8*)&ldsB[CB][offB[1]];                               \
    bfr[2] = *(const bf16x8*)&ldsB[CB][offB[2]];                               \
    bfr[3] = *(const bf16x8*)&ldsB[CB][offB[3]];                               \
    __builtin_amdgcn_s_setprio(1);                                             \
    _Pragma("unroll") for (int i = 0; i < 2; ++i)                              \
        _Pragma("unroll") for (int j = 0; j < 4; ++j) acc[i][j] =              \
        __builtin_amdgcn_mfma_f32_16x16x32_bf16(af[i], bfr[j], acc[i][j], 0,   \
                                                0, 0);                         \
    __builtin_amdgcn_s_setprio(0);                                             \
    *(u16x4*)&ldsA[NB][dstA] = lerp_pack(IC00, IC01, IC10, IC11, IWV);         \
    __builtin_amdgcn_sched_barrier(0);                                         \
    asm volatile("s_waitcnt vmcnt(4) lgkmcnt(0)" ::: "memory");                \
    __builtin_amdgcn_s_barrier();                                              \
    __builtin_amdgcn_sched_barrier(0);                                         \
  }

  int t = 0;
  for (int i35 = 0; i35 < 35; ++i35) {
    FUSED_STEP(0, 1, g1c00, g1c01, g1c10, g1c11, g1wv, g0c00, g0c01, g0c10,
               g0c11, g0wv)
    ++t;
    FUSED_STEP(1, 0, g0c00, g0c01, g0c10, g0c11, g0wv, g1c00, g1c01, g1c10,
               g1c11, g1wv)
    ++t;
  }
#undef FUSED_STEP

  // ---- peel t=70: consume g1 (tile 71), GLL B(71), full drain ----
  {
    GLL16(srcB0 + 71 * 32, &ldsB[1][tid * 8]);
    GLL16(srcB1 + 71 * 32, &ldsB[1][(512 + tid) * 8]);
    bf16x8 af[2], bfr[4];
    af[0] = *(const bf16x8*)&ldsA[0][offA[0]];
    af[1] = *(const bf16x8*)&ldsA[0][offA[1]];
#pragma unroll
    for (int f = 0; f < 4; ++f) bfr[f] = *(const bf16x8*)&ldsB[0][offB[f]];
#pragma unroll
    for (int i = 0; i < 2; ++i)
#pragma unroll
      for (int j = 0; j < 4; ++j)
        acc[i][j] = __builtin_amdgcn_mfma_f32_16x16x32_bf16(af[i], bfr[j],
                                                            acc[i][j], 0, 0, 0);
    *(u16x4*)&ldsA[1][dstA] = lerp_pack(g1c00, g1c01, g1c10, g1c11, g1wv);
    __syncthreads();
  }
  // ---- t=71 ----
  {
    bf16x8 af[2], bfr[4];
    af[0] = *(const bf16x8*)&ldsA[1][offA[0]];
    af[1] = *(const bf16x8*)&ldsA[1][offA[1]];
#pragma unroll
    for (int f = 0; f < 4; ++f) bfr[f] = *(const bf16x8*)&ldsB[1][offB[f]];
#pragma unroll
    for (int i = 0; i < 2; ++i)
#pragma unroll
      for (int j = 0; j < 4; ++j)
        acc[i][j] = __builtin_amdgcn_mfma_f32_16x16x32_bf16(af[i], bfr[j],
                                                            acc[i][j], 0, 0, 0);
  }

  // ---- epilogue ----
#pragma unroll
  for (int i = 0; i < 2; ++i) {
    const int m = m0 + wm * 32 + i * 16 + l4 * 4;
    const int bb = m >> 12;
    const int pos = m & 4095;
#pragma unroll
    for (int j = 0; j < 4; ++j) {
      const int o = wn * 64 + j * 16 + l15;
      *(f32x4*)(out + (((size_t)bb * OCH + o) << 12) + pos) = acc[i][j];
    }
  }
}

extern "C" void kernel_launch(void* const* d_in, const int* in_sizes, int n_in,
                              void* d_out, int out_size, void* d_ws,
                              size_t ws_size, hipStream_t stream) {
  const float* x = (const float*)d_in[0];
  const float* w_off = (const float*)d_in[1];
  const float* b_off = (const float*)d_in[2];
  const float* w_dcn = (const float*)d_in[3];
  float* out = (float*)d_out;

  char* ws = (char*)d_ws;
  float* off_buf = (float*)(ws);                            //  2,359,296 B
  unsigned short* Wop = (unsigned short*)(ws + 2359296);    //    147,456 B
  unsigned short* zp = (unsigned short*)(ws + 2506752);     //      1,024 B
  unsigned short* W2 = (unsigned short*)(ws + 2507776);     //  1,179,648 B
  unsigned short* xTbf = (unsigned short*)(ws + 3687424);   // 16,777,216 B
  // total 20,464,640 B

  prep<<<2304, 256, 0, stream>>>(w_dcn, w_off, W2, Wop, zp);
  xpose<<<2048, 256, 0, stream>>>(x, xTbf);
  offset_gemm<<<256, 256, 0, stream>>>(xTbf, Wop, zp, b_off, off_buf);
  dcn_fused<<<512, 512, 0, stream>>>(xTbf, off_buf, W2, out);
}